// Round 5
// baseline (132.134 us; speedup 1.0000x reference)
//
#include <hip/hip_runtime.h>

#define H 1024
#define W 1024
#define NIMG 8
#define TX 64
#define CY 8
#define TPB 8                       // y-tiles per persistent block
#define NBX (W / TX)                // 16
#define NBY (H / (CY * TPB))        // 16
#define NBLOCKS (NBX * NBY * NIMG)  // 2048 = exactly 8 blocks/CU
#define EPS 1e-5f

// Load 16 raw px of I and J for one rowsum unit (guarded at image edges).
__device__ __forceinline__ void load16(const float* __restrict__ Ip,
                                       const float* __restrict__ Jp,
                                       int y, int xbase, bool xfast,
                                       float* __restrict__ a,
                                       float* __restrict__ b) {
  if (y >= 0 && y < H) {
    const float* Irow = Ip + (size_t)y * W;
    const float* Jrow = Jp + (size_t)y * W;
    if (xfast) {
      const float4* pa = reinterpret_cast<const float4*>(Irow + xbase);
      const float4* pb = reinterpret_cast<const float4*>(Jrow + xbase);
      #pragma unroll
      for (int q = 0; q < 4; ++q) {
        float4 va = pa[q], vb = pb[q];
        a[4*q+0]=va.x; a[4*q+1]=va.y; a[4*q+2]=va.z; a[4*q+3]=va.w;
        b[4*q+0]=vb.x; b[4*q+1]=vb.y; b[4*q+2]=vb.z; b[4*q+3]=vb.w;
      }
    } else {
      #pragma unroll
      for (int k = 0; k < 16; ++k) {
        int xx = xbase + k;
        bool in = (xx >= 0) && (xx < W);
        a[k] = in ? Irow[xx] : 0.0f;
        b[k] = in ? Jrow[xx] : 0.0f;
      }
    }
  } else {
    #pragma unroll
    for (int k = 0; k < 16; ++k) { a[k] = 0.0f; b[k] = 0.0f; }
  }
}

// LDS: 16 rowsum rows x 64 cols x 20 B = 20480 B -> 8 blocks/CU.
__global__ __launch_bounds__(128, 4)
void ncc_main(const float* __restrict__ I, const float* __restrict__ J,
              float* __restrict__ partial) {
  __shared__ float4 rs4[16][TX];
  __shared__ float  rs1[16][TX];

  const int tid = threadIdx.x;
  const int gx = blockIdx.x, gy = blockIdx.y, n = blockIdx.z;
  const size_t img_off = (size_t)n * H * W;
  const float* Ip = I + img_off;
  const float* Jp = J + img_off;

  // phase-1 identity: one 8-px rowsum unit per thread, 16 rows x 8 xgroups
  const int r  = tid >> 3;            // 0..15
  const int xg = tid & 7;             // 0..7
  const int xg8 = xg * 8;
  const int xbase = gx * TX + xg8 - 4;
  const bool xfast = (xbase >= 0) && (xbase + 16 <= W);
  // phase-2 identity: 64 cols x 2 row-halves, 4 px each
  const int x  = tid & 63;
  const int hh = tid >> 6;
  const int xs = (x & ~7) | ((x ^ (x >> 3)) & 7);   // un-swizzle (const)
  const int pbase = hh * 4;

  const int y0 = gy * (CY * TPB);
  float abuf[2][16], bbuf[2][16];
  load16(Ip, Jp, y0 + r - 4, xbase, xfast, abuf[0], bbuf[0]);

  const float inv81 = 1.0f / 81.0f;
  float acc = 0.f;

  #pragma unroll
  for (int t = 0; t < TPB; ++t) {
    const int cb = t & 1, nb = cb ^ 1;
    // prefetch next tile's raw pixels (lands during this tile's compute)
    if (t < TPB - 1)
      load16(Ip, Jp, y0 + (t+1)*CY + r - 4, xbase, xfast, abuf[nb], bbuf[nb]);

    // ---- phase 1: horizontal 9-box sliding sums from current regs ----
    {
      const float* a = abuf[cb];
      const float* b = bbuf[cb];
      float sI=0.f, sJ=0.f, sII=0.f, sJJ=0.f, sIJ=0.f;
      #pragma unroll
      for (int k = 0; k < 9; ++k) {
        sI  += a[k];        sJ  += b[k];
        sII += a[k]*a[k];   sJJ += b[k]*b[k];
        sIJ += a[k]*b[k];
      }
      #pragma unroll
      for (int i = 0; i < 8; ++i) {
        if (i > 0) {
          float an=a[i+8], al=a[i-1], bn=b[i+8], bl=b[i-1];
          sI  += an - al;         sJ  += bn - bl;
          sII += an*an - al*al;   sJJ += bn*bn - bl*bl;
          sIJ += an*bn - al*bl;
        }
        const int px = xg8 + (i ^ xg);     // XOR swizzle across banks
        rs4[r][px] = make_float4(sI, sJ, sII, sJJ);
        rs1[r][px] = sIJ;
      }
    }
    __syncthreads();

    // ---- phase 2: vertical 9-box + cc for this tile's 8 rows ----
    {
      float4 rows4[9]; float rows1[9];
      float wI=0.f, wJ=0.f, wII=0.f, wJJ=0.f, wIJ=0.f;
      #pragma unroll
      for (int k = 0; k < 9; ++k) {
        rows4[k] = rs4[pbase + k][xs];
        rows1[k] = rs1[pbase + k][xs];
        wI += rows4[k].x; wJ += rows4[k].y;
        wII += rows4[k].z; wJJ += rows4[k].w;
        wIJ += rows1[k];
      }
      #pragma unroll
      for (int i = 0; i < 4; ++i) {
        if (i > 0) {
          float4 e4 = rs4[pbase + 8 + i][xs];
          float  e1 = rs1[pbase + 8 + i][xs];
          wI  += e4.x - rows4[i-1].x;  wJ  += e4.y - rows4[i-1].y;
          wII += e4.z - rows4[i-1].z;  wJJ += e4.w - rows4[i-1].w;
          wIJ += e1   - rows1[i-1];
        }
        float cross = fmaf(-(wI * wJ), inv81, wIJ);
        float Iv    = fmaf(-(wI * wI), inv81, wII);
        float Jv    = fmaf(-(wJ * wJ), inv81, wJJ);
        acc = fmaf(cross * cross,
                   __builtin_amdgcn_rcpf(fmaf(Iv, Jv, EPS)), acc);
      }
    }
    __syncthreads();   // phase-2 reads done before next iter's writes
  }

  // ---- block reduction -> partial (reuse rs1; last barrier above) ----
  #pragma unroll
  for (int off = 32; off > 0; off >>= 1)
    acc += __shfl_down(acc, off, 64);
  if ((tid & 63) == 0) rs1[0][tid >> 6] = acc;
  __syncthreads();
  if (tid == 0) {
    const int blin = blockIdx.x + NBX * (blockIdx.y + NBY * (int)blockIdx.z);
    partial[blin] = rs1[0][0] + rs1[0][1];
  }
}

__global__ __launch_bounds__(256)
void ncc_reduce(const float* __restrict__ partial, float* __restrict__ out) {
  __shared__ float red[4];
  const int tid = threadIdx.x;
  float s = 0.f;
  #pragma unroll 8
  for (int i = tid; i < NBLOCKS; i += 256) s += partial[i];
  #pragma unroll
  for (int off = 32; off > 0; off >>= 1)
    s += __shfl_down(s, off, 64);
  if ((tid & 63) == 0) red[tid >> 6] = s;
  __syncthreads();
  if (tid == 0)
    out[0] = (red[0] + red[1] + red[2] + red[3]) *
             (1.0f / (float)((size_t)NIMG * H * W));
}

extern "C" void kernel_launch(void* const* d_in, const int* in_sizes, int n_in,
                              void* d_out, int out_size, void* d_ws, size_t ws_size,
                              hipStream_t stream) {
  const float* I = (const float*)d_in[0];
  const float* J = (const float*)d_in[1];
  float* out     = (float*)d_out;
  float* partial = (float*)d_ws;            // 2048 * 4 B

  dim3 grid(NBX, NBY, NIMG);                // 16 x 16 x 8 = 2048 blocks
  hipLaunchKernelGGL(ncc_main, grid, dim3(128), 0, stream, I, J, partial);
  hipLaunchKernelGGL(ncc_reduce, dim3(1), dim3(256), 0, stream, partial, out);
}

// Round 6
// 119.940 us; speedup vs baseline: 1.1017x; 1.1017x over previous
//
#include <hip/hip_runtime.h>

#define H 1024
#define W 1024
#define NIMG 8
#define TX 64
#define CY 8
#define NBX (W / TX)                // 16
#define NBY (H / CY)                // 128
#define NBLOCKS (NBX * NBY * NIMG)  // 16384
#define EPS 1e-5f

// Load 16 raw px of I and J for one rowsum unit (guarded at image edges).
__device__ __forceinline__ void load16(const float* __restrict__ Ip,
                                       const float* __restrict__ Jp,
                                       int y, int xbase, bool xfast,
                                       float* __restrict__ a,
                                       float* __restrict__ b) {
  if (y >= 0 && y < H) {
    const float* Irow = Ip + (size_t)y * W;
    const float* Jrow = Jp + (size_t)y * W;
    if (xfast) {
      const float4* pa = reinterpret_cast<const float4*>(Irow + xbase);
      const float4* pb = reinterpret_cast<const float4*>(Jrow + xbase);
      #pragma unroll
      for (int q = 0; q < 4; ++q) {
        float4 va = pa[q], vb = pb[q];
        a[4*q+0]=va.x; a[4*q+1]=va.y; a[4*q+2]=va.z; a[4*q+3]=va.w;
        b[4*q+0]=vb.x; b[4*q+1]=vb.y; b[4*q+2]=vb.z; b[4*q+3]=vb.w;
      }
    } else {
      #pragma unroll
      for (int k = 0; k < 16; ++k) {
        int xx = xbase + k;
        bool in = (xx >= 0) && (xx < W);
        a[k] = in ? Irow[xx] : 0.0f;
        b[k] = in ? Jrow[xx] : 0.0f;
      }
    }
  } else {
    #pragma unroll
    for (int k = 0; k < 16; ++k) { a[k] = 0.0f; b[k] = 0.0f; }
  }
}

// Horizontal 9-box sliding sums for one row unit -> LDS (XOR-swizzled px).
__device__ __forceinline__ void rowsum8(const float* __restrict__ a,
                                        const float* __restrict__ b,
                                        int r, int xg,
                                        float4 (*rs4)[TX], float (*rs1)[TX]) {
  float sI=0.f, sJ=0.f, sII=0.f, sJJ=0.f, sIJ=0.f;
  #pragma unroll
  for (int k = 0; k < 9; ++k) {
    sI  += a[k];        sJ  += b[k];
    sII += a[k]*a[k];   sJJ += b[k]*b[k];
    sIJ += a[k]*b[k];
  }
  const int xg8 = xg * 8;
  #pragma unroll
  for (int i = 0; i < 8; ++i) {
    if (i > 0) {
      float an=a[i+8], al=a[i-1], bn=b[i+8], bl=b[i-1];
      sI  += an - al;         sJ  += bn - bl;
      sII += an*an - al*al;   sJJ += bn*bn - bl*bl;
      sIJ += an*bn - al*bl;
    }
    const int px = xg8 + (i ^ xg);
    rs4[r][px] = make_float4(sI, sJ, sII, sJJ);
    rs1[r][px] = sIJ;
  }
}

// Single-wave blocks: LDS = 16*64*20 B = 20480 B -> 8 blocks/CU, and no
// inter-wave barrier coupling at all (self-paced waves).
__global__ __launch_bounds__(64, 2)
void ncc_main(const float* __restrict__ I, const float* __restrict__ J,
              float* __restrict__ partial) {
  __shared__ float4 rs4[16][TX];
  __shared__ float  rs1[16][TX];

  const int tid = threadIdx.x;            // 0..63
  const int gx = blockIdx.x, gy = blockIdx.y, n = blockIdx.z;
  const size_t img_off = (size_t)n * H * W;
  const float* Ip = I + img_off;
  const float* Jp = J + img_off;

  // ---- Phase 1: two rowsum units per thread (rows rb and rb+8) ----
  const int rb = tid >> 3;                // 0..7
  const int xg = tid & 7;                 // 0..7
  const int xbase = gx * TX + xg * 8 - 4;
  const bool xfast = (xbase >= 0) && (xbase + 16 <= W);
  const int ybase = gy * CY - 4;

  float a0[16], b0[16], a1[16], b1[16];
  // issue all 16 float4 loads before any use: full memory-level parallelism
  load16(Ip, Jp, ybase + rb,     xbase, xfast, a0, b0);
  load16(Ip, Jp, ybase + rb + 8, xbase, xfast, a1, b1);
  rowsum8(a0, b0, rb,     xg, rs4, rs1);
  rowsum8(a1, b1, rb + 8, xg, rs4, rs1);
  __syncthreads();                        // single-wave: cheap

  // ---- Phase 2: one full column per thread (8 output rows) ----
  const int x  = tid;
  const int xs = (x & ~7) | ((x ^ (x >> 3)) & 7);   // un-swizzle (const)
  float4 h4[16]; float h1[16];
  #pragma unroll
  for (int k = 0; k < 16; ++k) { h4[k] = rs4[k][xs]; h1[k] = rs1[k][xs]; }

  float wI=0.f, wJ=0.f, wII=0.f, wJJ=0.f, wIJ=0.f;
  #pragma unroll
  for (int k = 0; k < 9; ++k) {
    wI += h4[k].x; wJ += h4[k].y; wII += h4[k].z; wJJ += h4[k].w;
    wIJ += h1[k];
  }
  const float inv81 = 1.0f / 81.0f;
  float acc = 0.f;
  #pragma unroll
  for (int i = 0; i < 8; ++i) {
    if (i > 0) {
      wI  += h4[8+i].x - h4[i-1].x;  wJ  += h4[8+i].y - h4[i-1].y;
      wII += h4[8+i].z - h4[i-1].z;  wJJ += h4[8+i].w - h4[i-1].w;
      wIJ += h1[8+i]   - h1[i-1];
    }
    float cross = fmaf(-(wI * wJ), inv81, wIJ);
    float Iv    = fmaf(-(wI * wI), inv81, wII);
    float Jv    = fmaf(-(wJ * wJ), inv81, wJJ);
    acc = fmaf(cross * cross,
               __builtin_amdgcn_rcpf(fmaf(Iv, Jv, EPS)), acc);
  }

  // ---- wave reduction -> partial (no LDS, no barrier) ----
  #pragma unroll
  for (int off = 32; off > 0; off >>= 1)
    acc += __shfl_down(acc, off, 64);
  if (tid == 0) {
    const int blin = blockIdx.x + NBX * (blockIdx.y + NBY * (int)blockIdx.z);
    partial[blin] = acc;
  }
}

__global__ __launch_bounds__(256)
void ncc_reduce(const float* __restrict__ partial, float* __restrict__ out) {
  __shared__ float red[4];
  const int tid = threadIdx.x;
  const float4* p4 = reinterpret_cast<const float4*>(partial);
  float s = 0.f;
  #pragma unroll 4
  for (int i = tid; i < NBLOCKS / 4; i += 256) {
    float4 v = p4[i];
    s += (v.x + v.y) + (v.z + v.w);
  }
  #pragma unroll
  for (int off = 32; off > 0; off >>= 1)
    s += __shfl_down(s, off, 64);
  if ((tid & 63) == 0) red[tid >> 6] = s;
  __syncthreads();
  if (tid == 0)
    out[0] = (red[0] + red[1] + red[2] + red[3]) *
             (1.0f / (float)((size_t)NIMG * H * W));
}

extern "C" void kernel_launch(void* const* d_in, const int* in_sizes, int n_in,
                              void* d_out, int out_size, void* d_ws, size_t ws_size,
                              hipStream_t stream) {
  const float* I = (const float*)d_in[0];
  const float* J = (const float*)d_in[1];
  float* out     = (float*)d_out;
  float* partial = (float*)d_ws;            // 16384 * 4 B = 64 KiB scratch

  dim3 grid(NBX, NBY, NIMG);                // 16 x 128 x 8 = 16384 blocks
  hipLaunchKernelGGL(ncc_main, grid, dim3(64), 0, stream, I, J, partial);
  hipLaunchKernelGGL(ncc_reduce, dim3(1), dim3(256), 0, stream, partial, out);
}

// Round 7
// 110.977 us; speedup vs baseline: 1.1906x; 1.0808x over previous
//
#include <hip/hip_runtime.h>

#define H 1024
#define W 1024
#define NIMG 8
#define CPT 4                  // columns per thread
#define TH 16                  // output rows per wave-tile
#define NBX 4                  // x-quadrants: 64 lanes * 4 cols * 4 = 1024
#define WPB 4                  // waves per block, stacked in y
#define NBY (H / (TH * WPB))   // 16
#define NWAVES (NBX * NBY * NIMG * WPB)   // 2048
#define EPS 1e-5f

struct RS { float I[CPT], J[CPT], II[CPT], JJ[CPT], IJ[CPT]; };

// Horizontal 9-box rowsums for 4 consecutive output columns [X, X+4),
// from 12 raw px per image (aligned float4 loads, edge-guarded).
__device__ __forceinline__ void row_rs(const float* __restrict__ Irow,
                                       const float* __restrict__ Jrow,
                                       int X, bool okL, bool okR, RS& o) {
  float a[12], b[12];
  { float4 q = *reinterpret_cast<const float4*>(Irow + X);
    a[4]=q.x; a[5]=q.y; a[6]=q.z; a[7]=q.w;
    float4 p = *reinterpret_cast<const float4*>(Jrow + X);
    b[4]=p.x; b[5]=p.y; b[6]=p.z; b[7]=p.w; }
  if (okL) {
    float4 q = *reinterpret_cast<const float4*>(Irow + X - 4);
    a[0]=q.x; a[1]=q.y; a[2]=q.z; a[3]=q.w;
    float4 p = *reinterpret_cast<const float4*>(Jrow + X - 4);
    b[0]=p.x; b[1]=p.y; b[2]=p.z; b[3]=p.w;
  } else { a[0]=a[1]=a[2]=a[3]=0.f; b[0]=b[1]=b[2]=b[3]=0.f; }
  if (okR) {
    float4 q = *reinterpret_cast<const float4*>(Irow + X + 4);
    a[8]=q.x; a[9]=q.y; a[10]=q.z; a[11]=q.w;
    float4 p = *reinterpret_cast<const float4*>(Jrow + X + 4);
    b[8]=p.x; b[9]=p.y; b[10]=p.z; b[11]=p.w;
  } else { a[8]=a[9]=a[10]=a[11]=0.f; b[8]=b[9]=b[10]=b[11]=0.f; }

  float sI=0.f, sJ=0.f, sII=0.f, sJJ=0.f, sIJ=0.f;
  #pragma unroll
  for (int k = 0; k < 9; ++k) {
    sI += a[k]; sJ += b[k];
    sII = fmaf(a[k], a[k], sII);
    sJJ = fmaf(b[k], b[k], sJJ);
    sIJ = fmaf(a[k], b[k], sIJ);
  }
  o.I[0]=sI; o.J[0]=sJ; o.II[0]=sII; o.JJ[0]=sJJ; o.IJ[0]=sIJ;
  #pragma unroll
  for (int i = 1; i < CPT; ++i) {
    float an=a[i+8], al=a[i-1], bn=b[i+8], bl=b[i-1];
    sI += an - al;  sJ += bn - bl;
    sII = fmaf(-al, al, fmaf(an, an, sII));
    sJJ = fmaf(-bl, bl, fmaf(bn, bn, sJJ));
    sIJ = fmaf(-al, bl, fmaf(an, bn, sIJ));
    o.I[i]=sI; o.J[i]=sJ; o.II[i]=sII; o.JJ[i]=sJJ; o.IJ[i]=sIJ;
  }
}

// No LDS, no barriers: each wave independently walks a 256-col x 16-row tile,
// each thread a 4-col strip with vertical running window sums in registers.
// Leaving rows are re-loaded (L1/L2-hot) and recomputed instead of ring-kept.
__global__ __launch_bounds__(256, 2)
void ncc_main(const float* __restrict__ I, const float* __restrict__ J,
              float* __restrict__ partial) {
  const int tid  = threadIdx.x;
  const int lane = tid & 63, wv = tid >> 6;
  const int X  = blockIdx.x * 256 + lane * CPT;
  const int y0 = (blockIdx.y * WPB + wv) * TH;
  const bool okL = (X >= 4);
  const bool okR = (X + 8 <= W);
  const size_t img_off = (size_t)blockIdx.z * H * W;
  const float* Ip = I + img_off;
  const float* Jp = J + img_off;

  float wI[CPT], wJ[CPT], wII[CPT], wJJ[CPT], wIJ[CPT];
  #pragma unroll
  for (int i = 0; i < CPT; ++i) { wI[i]=wJ[i]=wII[i]=wJJ[i]=wIJ[i]=0.f; }
  float acc = 0.f;
  const float inv81 = 1.0f / 81.0f;

  // sgn=+1: add row r's rowsums into window; sgn=-1: subtract (leave)
  auto apply = [&](int r, float sgn) {
    if ((unsigned)r < (unsigned)H) {
      RS o;
      row_rs(Ip + (size_t)r * W, Jp + (size_t)r * W, X, okL, okR, o);
      #pragma unroll
      for (int i = 0; i < CPT; ++i) {
        wI[i]  = fmaf(sgn, o.I[i],  wI[i]);
        wJ[i]  = fmaf(sgn, o.J[i],  wJ[i]);
        wII[i] = fmaf(sgn, o.II[i], wII[i]);
        wJJ[i] = fmaf(sgn, o.JJ[i], wJJ[i]);
        wIJ[i] = fmaf(sgn, o.IJ[i], wIJ[i]);
      }
    }
  };
  auto emit = [&]() {
    #pragma unroll
    for (int i = 0; i < CPT; ++i) {
      float cross = fmaf(-(wI[i] * wJ[i]), inv81, wIJ[i]);
      float Iv    = fmaf(-(wI[i] * wI[i]), inv81, wII[i]);
      float Jv    = fmaf(-(wJ[i] * wJ[i]), inv81, wJJ[i]);
      acc = fmaf(cross * cross,
                 __builtin_amdgcn_rcpf(fmaf(Iv, Jv, EPS)), acc);
    }
  };

  // warm-up: rows y0-4 .. y0+3
  for (int k = 0; k < 8; ++k) apply(y0 - 4 + k, 1.0f);
  // first output row: add y0+4, window = rows y0-4..y0+4
  apply(y0 + 4, 1.0f);
  emit();
  // steady state: add r, drop r-9, emit y=r-4
  for (int k = 0; k < TH - 1; ++k) {
    apply(y0 + 5 + k, 1.0f);
    apply(y0 - 4 + k, -1.0f);
    emit();
  }

  // wave reduction -> one partial per wave (no LDS, no barrier)
  #pragma unroll
  for (int off = 32; off > 0; off >>= 1)
    acc += __shfl_down(acc, off, 64);
  if (lane == 0) {
    const int wid = (((int)blockIdx.z * NBY + (int)blockIdx.y) * NBX
                     + (int)blockIdx.x) * WPB + wv;
    partial[wid] = acc;
  }
}

__global__ __launch_bounds__(256)
void ncc_reduce(const float* __restrict__ partial, float* __restrict__ out) {
  __shared__ float red[4];
  const int tid = threadIdx.x;
  const float4* p4 = reinterpret_cast<const float4*>(partial);
  float s = 0.f;
  #pragma unroll
  for (int i = tid; i < NWAVES / 4; i += 256) {
    float4 v = p4[i];
    s += (v.x + v.y) + (v.z + v.w);
  }
  #pragma unroll
  for (int off = 32; off > 0; off >>= 1)
    s += __shfl_down(s, off, 64);
  if ((tid & 63) == 0) red[tid >> 6] = s;
  __syncthreads();
  if (tid == 0)
    out[0] = (red[0] + red[1] + red[2] + red[3]) *
             (1.0f / (float)((size_t)NIMG * H * W));
}

extern "C" void kernel_launch(void* const* d_in, const int* in_sizes, int n_in,
                              void* d_out, int out_size, void* d_ws, size_t ws_size,
                              hipStream_t stream) {
  const float* I = (const float*)d_in[0];
  const float* J = (const float*)d_in[1];
  float* out     = (float*)d_out;
  float* partial = (float*)d_ws;            // 2048 * 4 B

  dim3 grid(NBX, NBY, NIMG);                // 4 x 16 x 8 = 512 blocks, 2/CU
  hipLaunchKernelGGL(ncc_main, grid, dim3(256), 0, stream, I, J, partial);
  hipLaunchKernelGGL(ncc_reduce, dim3(1), dim3(256), 0, stream, partial, out);
}